// Round 1
// baseline (10569.019 us; speedup 1.0000x reference)
//
#include <hip/hip_runtime.h>

#define N_NODES   100000
#define N_EDGES   1600000
#define WALK_LEN  16
#define OUT_DIM   8
#define N_PROBES  32

// ---------------- degree ----------------
__global__ void deg_kernel(const int* __restrict__ row, int* __restrict__ deg) {
    int e = blockIdx.x * blockDim.x + threadIdx.x;
    if (e < N_EDGES) atomicAdd(&deg[row[e]], 1);
}

__global__ void rw_kernel(const int* __restrict__ row, const int* __restrict__ deg,
                          float* __restrict__ rw) {
    int e = blockIdx.x * blockDim.x + threadIdx.x;
    if (e < N_EDGES) {
        int d = deg[row[e]];
        rw[e] = 1.0f / (float)(d > 0 ? d : 1);
    }
}

// ---------------- one sparse transition: p_new[col] += p_cur[row] * rw ----------------
// 8 threads per edge, each handles 4 probes (float4 gather + 4 atomic adds).
__global__ void scatter_kernel(const int* __restrict__ row, const int* __restrict__ col,
                               const float* __restrict__ rw,
                               const float* __restrict__ p_cur, float* __restrict__ p_new) {
    int gid = blockIdx.x * blockDim.x + threadIdx.x;   // [0, E*8)
    int e = gid >> 3;
    int j = (gid & 7) << 2;
    if (e >= N_EDGES) return;
    int r = row[e];
    int c = col[e];
    float w = rw[e];
    const float4 v = *reinterpret_cast<const float4*>(p_cur + (size_t)r * N_PROBES + j);
    float* dst = p_new + (size_t)c * N_PROBES + j;
    atomicAdd(dst + 0, v.x * w);
    atomicAdd(dst + 1, v.y * w);
    atomicAdd(dst + 2, v.z * w);
    atomicAdd(dst + 3, v.w * w);
}

// ---------------- Hutchinson diag for this step + zero the consumed buffer ----------------
// One thread per (node, probe) element; 32-lane segmented shuffle reduction.
__global__ void diag_kernel(const float* __restrict__ probes, const float* __restrict__ p_new,
                            float* __restrict__ diag_row, float* __restrict__ zero_buf) {
    int gid = blockIdx.x * blockDim.x + threadIdx.x;   // [0, N*32), exact multiple of 256
    float prod = probes[gid] * p_new[gid];
    // reduce across the 32 probes (aligned 32-lane segments of the wave)
    for (int off = 16; off > 0; off >>= 1)
        prod += __shfl_down(prod, off, 32);
    if ((gid & 31) == 0) {
        diag_row[gid >> 5] = prod * (1.0f / (float)N_PROBES);
    }
    if (zero_buf) zero_buf[gid] = 0.0f;
}

// ---------------- out[n] = diags[n,:] @ W^T + b ----------------
__global__ void out_kernel(const float* __restrict__ diags, const float* __restrict__ W,
                           const float* __restrict__ b, float* __restrict__ out) {
    int n = blockIdx.x * blockDim.x + threadIdx.x;
    if (n >= N_NODES) return;
    float d[WALK_LEN];
#pragma unroll
    for (int k = 0; k < WALK_LEN; k++) d[k] = diags[(size_t)k * N_NODES + n];
    float o[OUT_DIM];
#pragma unroll
    for (int j = 0; j < OUT_DIM; j++) {
        float acc = b[j];
#pragma unroll
        for (int k = 0; k < WALK_LEN; k++) acc += d[k] * W[j * WALK_LEN + k];
        o[j] = acc;
    }
    float4* outp = reinterpret_cast<float4*>(out + (size_t)n * OUT_DIM);
    outp[0] = make_float4(o[0], o[1], o[2], o[3]);
    outp[1] = make_float4(o[4], o[5], o[6], o[7]);
}

extern "C" void kernel_launch(void* const* d_in, const int* in_sizes, int n_in,
                              void* d_out, int out_size, void* d_ws, size_t ws_size,
                              hipStream_t stream) {
    const int*   edge_index = (const int*)d_in[0];
    const int*   row    = edge_index;
    const int*   col    = edge_index + N_EDGES;
    const float* probes = (const float*)d_in[2];
    const float* W      = (const float*)d_in[3];
    const float* b      = (const float*)d_in[4];
    float*       out    = (float*)d_out;

    // workspace carve-up (256B aligned)
    char* ws = (char*)d_ws;
    size_t off = 0;
    auto carve = [&](size_t bytes) -> void* {
        void* p = ws + off;
        off += (bytes + 255) & ~(size_t)255;
        return p;
    };
    int*   deg   = (int*)  carve((size_t)N_NODES * 4);            // 400 KB
    float* rw    = (float*)carve((size_t)N_EDGES * 4);            // 6.4 MB
    float* bufA  = (float*)carve((size_t)N_NODES * N_PROBES * 4); // 12.8 MB
    float* bufB  = (float*)carve((size_t)N_NODES * N_PROBES * 4); // 12.8 MB
    float* diags = (float*)carve((size_t)WALK_LEN * N_NODES * 4); // 6.4 MB

    // zero-init (ws is poisoned 0xAA before every call)
    hipMemsetAsync(deg,  0, (size_t)N_NODES * 4, stream);
    hipMemsetAsync(bufA, 0, (size_t)N_NODES * N_PROBES * 4, stream);
    hipMemsetAsync(bufB, 0, (size_t)N_NODES * N_PROBES * 4, stream);

    const int B = 256;
    deg_kernel<<<(N_EDGES + B - 1) / B, B, 0, stream>>>(row, deg);
    rw_kernel <<<(N_EDGES + B - 1) / B, B, 0, stream>>>(row, deg, rw);

    const float* cur = probes;
    for (int k = 0; k < WALK_LEN; k++) {
        float* nxt = (k & 1) ? bufB : bufA;
        scatter_kernel<<<(N_EDGES * 8) / B, B, 0, stream>>>(row, col, rw, cur, nxt);
        // fuse: zero the buffer we just consumed (it becomes the scatter target of step k+1)
        float* zb = (k == 0) ? nullptr : (float*)cur;
        diag_kernel<<<(N_NODES * N_PROBES) / B, B, 0, stream>>>(probes, nxt,
                                                                diags + (size_t)k * N_NODES, zb);
        cur = nxt;
    }

    out_kernel<<<(N_NODES + B - 1) / B, B, 0, stream>>>(diags, W, b, out);
}

// Round 2
// 944.481 us; speedup vs baseline: 11.1903x; 11.1903x over previous
//
#include <hip/hip_runtime.h>

#define N_NODES   100000
#define N_EDGES   1600000
#define WALK_LEN  16
#define OUT_DIM   8
#define N_PROBES  32

#define SCAN_BLK  256
#define NBLK      ((N_NODES + SCAN_BLK - 1) / SCAN_BLK)   // 391

// ---------------- degree counts ----------------
__global__ void deg_kernel(const int* __restrict__ row, const int* __restrict__ col,
                           int* __restrict__ outdeg, int* __restrict__ indeg) {
    int e = blockIdx.x * blockDim.x + threadIdx.x;
    if (e < N_EDGES) {
        atomicAdd(&outdeg[row[e]], 1);
        atomicAdd(&indeg[col[e]], 1);
    }
}

// ---------------- prefix scan of indeg -> offs (exclusive) ----------------
__global__ void scan1_kernel(const int* __restrict__ indeg, int* __restrict__ bsum) {
    __shared__ int s[SCAN_BLK];
    int i = blockIdx.x * SCAN_BLK + threadIdx.x;
    s[threadIdx.x] = (i < N_NODES) ? indeg[i] : 0;
    __syncthreads();
    for (int o = SCAN_BLK / 2; o > 0; o >>= 1) {
        if (threadIdx.x < o) s[threadIdx.x] += s[threadIdx.x + o];
        __syncthreads();
    }
    if (threadIdx.x == 0) bsum[blockIdx.x] = s[0];
}

__global__ void scan2_kernel(int* __restrict__ bsum) {   // single block of 512
    __shared__ int s[512];
    int t = threadIdx.x;
    s[t] = (t < NBLK) ? bsum[t] : 0;
    __syncthreads();
    for (int o = 1; o < 512; o <<= 1) {
        int v = (t >= o) ? s[t - o] : 0;
        __syncthreads();
        s[t] += v;
        __syncthreads();
    }
    if (t < NBLK) bsum[t] = (t == 0) ? 0 : s[t - 1];     // exclusive
}

__global__ void scan3_kernel(const int* __restrict__ indeg, const int* __restrict__ bsum,
                             int* __restrict__ offs) {
    __shared__ int s[SCAN_BLK];
    int t = threadIdx.x;
    int i = blockIdx.x * SCAN_BLK + t;
    int v = (i < N_NODES) ? indeg[i] : 0;
    s[t] = v;
    __syncthreads();
    for (int o = 1; o < SCAN_BLK; o <<= 1) {
        int u = (t >= o) ? s[t - o] : 0;
        __syncthreads();
        s[t] += u;
        __syncthreads();
    }
    if (i < N_NODES) offs[i] = bsum[blockIdx.x] + s[t] - v;   // exclusive
}

// ---------------- counting-sort fill of CSC ----------------
__global__ void fill_kernel(const int* __restrict__ row, const int* __restrict__ col,
                            const int* __restrict__ outdeg, const int* __restrict__ offs,
                            int* __restrict__ cursor,
                            int* __restrict__ csc_row, float* __restrict__ csc_w) {
    int e = blockIdx.x * blockDim.x + threadIdx.x;
    if (e >= N_EDGES) return;
    int r = row[e], c = col[e];
    int idx = offs[c] + atomicAdd(&cursor[c], 1);
    csc_row[idx] = r;
    int d = outdeg[r];
    csc_w[idx] = 1.0f / (float)(d > 0 ? d : 1);
}

// ---------------- fused transition (gather-reduce) + Hutchinson diag ----------------
// 8 threads per node; thread (n, j) owns probes [4j, 4j+4).
__global__ void gather_kernel(const int* __restrict__ offs, const int* __restrict__ indeg,
                              const int* __restrict__ csc_row, const float* __restrict__ csc_w,
                              const float* __restrict__ p_cur, const float* __restrict__ probes,
                              float* __restrict__ p_new, float* __restrict__ diag_row) {
    int gid = blockIdx.x * blockDim.x + threadIdx.x;   // [0, N*8) exact
    int n = gid >> 3;
    int j = (gid & 7) << 2;
    int start = offs[n];
    int cnt   = indeg[n];
    float4 acc = make_float4(0.f, 0.f, 0.f, 0.f);
    for (int q = 0; q < cnt; q++) {
        int   r = csc_row[start + q];
        float w = csc_w[start + q];
        const float4 v = *reinterpret_cast<const float4*>(p_cur + (size_t)r * N_PROBES + j);
        acc.x += v.x * w;
        acc.y += v.y * w;
        acc.z += v.z * w;
        acc.w += v.w * w;
    }
    *reinterpret_cast<float4*>(p_new + (size_t)n * N_PROBES + j) = acc;
    const float4 pr = *reinterpret_cast<const float4*>(probes + (size_t)n * N_PROBES + j);
    float dot = acc.x * pr.x + acc.y * pr.y + acc.z * pr.z + acc.w * pr.w;
    dot += __shfl_xor(dot, 4, 8);
    dot += __shfl_xor(dot, 2, 8);
    dot += __shfl_xor(dot, 1, 8);
    if ((gid & 7) == 0) diag_row[n] = dot * (1.0f / (float)N_PROBES);
}

// ---------------- out[n] = diags[n,:] @ W^T + b ----------------
__global__ void out_kernel(const float* __restrict__ diags, const float* __restrict__ W,
                           const float* __restrict__ b, float* __restrict__ out) {
    int n = blockIdx.x * blockDim.x + threadIdx.x;
    if (n >= N_NODES) return;
    float d[WALK_LEN];
#pragma unroll
    for (int k = 0; k < WALK_LEN; k++) d[k] = diags[(size_t)k * N_NODES + n];
    float o[OUT_DIM];
#pragma unroll
    for (int j = 0; j < OUT_DIM; j++) {
        float acc = b[j];
#pragma unroll
        for (int k = 0; k < WALK_LEN; k++) acc += d[k] * W[j * WALK_LEN + k];
        o[j] = acc;
    }
    float4* outp = reinterpret_cast<float4*>(out + (size_t)n * OUT_DIM);
    outp[0] = make_float4(o[0], o[1], o[2], o[3]);
    outp[1] = make_float4(o[4], o[5], o[6], o[7]);
}

extern "C" void kernel_launch(void* const* d_in, const int* in_sizes, int n_in,
                              void* d_out, int out_size, void* d_ws, size_t ws_size,
                              hipStream_t stream) {
    const int*   edge_index = (const int*)d_in[0];
    const int*   row    = edge_index;
    const int*   col    = edge_index + N_EDGES;
    const float* probes = (const float*)d_in[2];
    const float* W      = (const float*)d_in[3];
    const float* b      = (const float*)d_in[4];
    float*       out    = (float*)d_out;

    // workspace carve-up (256B aligned)
    char* ws = (char*)d_ws;
    size_t off = 0;
    auto carve = [&](size_t bytes) -> void* {
        void* p = ws + off;
        off += (bytes + 255) & ~(size_t)255;
        return p;
    };
    int*   outdeg  = (int*)  carve((size_t)N_NODES * 4);            // 400 KB
    int*   indeg   = (int*)  carve((size_t)N_NODES * 4);            // 400 KB
    int*   cursor  = (int*)  carve((size_t)N_NODES * 4);            // 400 KB
    int*   offs    = (int*)  carve((size_t)N_NODES * 4);            // 400 KB
    int*   bsum    = (int*)  carve((size_t)NBLK * 4);               // ~1.6 KB
    int*   csc_row = (int*)  carve((size_t)N_EDGES * 4);            // 6.4 MB
    float* csc_w   = (float*)carve((size_t)N_EDGES * 4);            // 6.4 MB
    float* bufA    = (float*)carve((size_t)N_NODES * N_PROBES * 4); // 12.8 MB
    float* bufB    = (float*)carve((size_t)N_NODES * N_PROBES * 4); // 12.8 MB
    float* diags   = (float*)carve((size_t)WALK_LEN * N_NODES * 4); // 6.4 MB

    hipMemsetAsync(outdeg, 0, (size_t)N_NODES * 4, stream);
    hipMemsetAsync(indeg,  0, (size_t)N_NODES * 4, stream);
    hipMemsetAsync(cursor, 0, (size_t)N_NODES * 4, stream);

    const int B = 256;
    // ---- build CSC (once per call, reused by 16 transitions) ----
    deg_kernel  <<<(N_EDGES + B - 1) / B, B, 0, stream>>>(row, col, outdeg, indeg);
    scan1_kernel<<<NBLK, SCAN_BLK, 0, stream>>>(indeg, bsum);
    scan2_kernel<<<1, 512, 0, stream>>>(bsum);
    scan3_kernel<<<NBLK, SCAN_BLK, 0, stream>>>(indeg, bsum, offs);
    fill_kernel <<<(N_EDGES + B - 1) / B, B, 0, stream>>>(row, col, outdeg, offs, cursor,
                                                          csc_row, csc_w);

    // ---- 16 fused transition + diag steps (no atomics, no memsets) ----
    const float* cur = probes;
    for (int k = 0; k < WALK_LEN; k++) {
        float* nxt = (k & 1) ? bufB : bufA;
        gather_kernel<<<(N_NODES * 8 + B - 1) / B, B, 0, stream>>>(
            offs, indeg, csc_row, csc_w, cur, probes, nxt, diags + (size_t)k * N_NODES);
        cur = nxt;
    }

    out_kernel<<<(N_NODES + B - 1) / B, B, 0, stream>>>(diags, W, b, out);
}

// Round 3
// 766.405 us; speedup vs baseline: 13.7904x; 1.2324x over previous
//
#include <hip/hip_runtime.h>

#define N_NODES   100000
#define N_EDGES   1600000
#define WALK_LEN  16
#define OUT_DIM   8
#define N_PROBES  32

#define SCAN_BLK  256
#define NBLK      ((N_NODES + SCAN_BLK - 1) / SCAN_BLK)   // 391

// ---------------- degrees + ticket (slot rank per edge) in one pass ----------------
__global__ void deg_ticket_kernel(const int* __restrict__ row, const int* __restrict__ col,
                                  int* __restrict__ outdeg, int* __restrict__ indeg,
                                  int* __restrict__ ticket) {
    int e = blockIdx.x * blockDim.x + threadIdx.x;
    if (e < N_EDGES) {
        atomicAdd(&outdeg[row[e]], 1);
        ticket[e] = atomicAdd(&indeg[col[e]], 1);
    }
}

__global__ void inv_kernel(const int* __restrict__ outdeg, float* __restrict__ inv_outdeg) {
    int n = blockIdx.x * blockDim.x + threadIdx.x;
    if (n < N_NODES) {
        int d = outdeg[n];
        inv_outdeg[n] = 1.0f / (float)(d > 0 ? d : 1);
    }
}

// ---------------- prefix scan of indeg -> offs (exclusive) ----------------
__global__ void scan1_kernel(const int* __restrict__ indeg, int* __restrict__ bsum) {
    __shared__ int s[SCAN_BLK];
    int i = blockIdx.x * SCAN_BLK + threadIdx.x;
    s[threadIdx.x] = (i < N_NODES) ? indeg[i] : 0;
    __syncthreads();
    for (int o = SCAN_BLK / 2; o > 0; o >>= 1) {
        if (threadIdx.x < o) s[threadIdx.x] += s[threadIdx.x + o];
        __syncthreads();
    }
    if (threadIdx.x == 0) bsum[blockIdx.x] = s[0];
}

__global__ void scan2_kernel(int* __restrict__ bsum) {   // single block of 512
    __shared__ int s[512];
    int t = threadIdx.x;
    s[t] = (t < NBLK) ? bsum[t] : 0;
    __syncthreads();
    for (int o = 1; o < 512; o <<= 1) {
        int v = (t >= o) ? s[t - o] : 0;
        __syncthreads();
        s[t] += v;
        __syncthreads();
    }
    if (t < NBLK) bsum[t] = (t == 0) ? 0 : s[t - 1];     // exclusive
}

__global__ void scan3_kernel(const int* __restrict__ indeg, const int* __restrict__ bsum,
                             int* __restrict__ offs) {
    __shared__ int s[SCAN_BLK];
    int t = threadIdx.x;
    int i = blockIdx.x * SCAN_BLK + t;
    int v = (i < N_NODES) ? indeg[i] : 0;
    s[t] = v;
    __syncthreads();
    for (int o = 1; o < SCAN_BLK; o <<= 1) {
        int u = (t >= o) ? s[t - o] : 0;
        __syncthreads();
        s[t] += u;
        __syncthreads();
    }
    if (i < N_NODES) offs[i] = bsum[blockIdx.x] + s[t] - v;   // exclusive
}

// ---------------- atomic-free CSC fill using tickets ----------------
__global__ void place_kernel(const int* __restrict__ row, const int* __restrict__ col,
                             const int* __restrict__ ticket, const int* __restrict__ offs,
                             int* __restrict__ csc_row) {
    int e = blockIdx.x * blockDim.x + threadIdx.x;
    if (e >= N_EDGES) return;
    csc_row[offs[col[e]] + ticket[e]] = row[e];
}

// ---------------- s0 = probes * inv_outdeg ----------------
__global__ void s0_kernel(const float* __restrict__ probes, const float* __restrict__ inv_outdeg,
                          float* __restrict__ s0) {
    int gid = blockIdx.x * blockDim.x + threadIdx.x;   // [0, N*32)
    s0[gid] = probes[gid] * inv_outdeg[gid >> 5];
}

// ---------------- fused unweighted gather + rescale + Hutchinson diag ----------------
// 8 threads per node; thread (n, j) owns probes [4j, 4j+4).
__global__ void gather_kernel(const int* __restrict__ offs, const int* __restrict__ indeg,
                              const int* __restrict__ csc_row,
                              const float* __restrict__ s_cur, const float* __restrict__ probes,
                              const float* __restrict__ inv_outdeg,
                              float* __restrict__ s_new, float* __restrict__ diag_row) {
    int gid = blockIdx.x * blockDim.x + threadIdx.x;   // [0, N*8) exact
    int n = gid >> 3;
    int j = (gid & 7) << 2;
    int start = offs[n];
    int cnt   = indeg[n];
    float inv = inv_outdeg[n];
    float4 acc = make_float4(0.f, 0.f, 0.f, 0.f);
    int q = 0;
    for (; q + 8 <= cnt; q += 8) {
        int r0 = csc_row[start + q + 0];
        int r1 = csc_row[start + q + 1];
        int r2 = csc_row[start + q + 2];
        int r3 = csc_row[start + q + 3];
        int r4 = csc_row[start + q + 4];
        int r5 = csc_row[start + q + 5];
        int r6 = csc_row[start + q + 6];
        int r7 = csc_row[start + q + 7];
        float4 v0 = *reinterpret_cast<const float4*>(s_cur + (size_t)r0 * N_PROBES + j);
        float4 v1 = *reinterpret_cast<const float4*>(s_cur + (size_t)r1 * N_PROBES + j);
        float4 v2 = *reinterpret_cast<const float4*>(s_cur + (size_t)r2 * N_PROBES + j);
        float4 v3 = *reinterpret_cast<const float4*>(s_cur + (size_t)r3 * N_PROBES + j);
        float4 v4 = *reinterpret_cast<const float4*>(s_cur + (size_t)r4 * N_PROBES + j);
        float4 v5 = *reinterpret_cast<const float4*>(s_cur + (size_t)r5 * N_PROBES + j);
        float4 v6 = *reinterpret_cast<const float4*>(s_cur + (size_t)r6 * N_PROBES + j);
        float4 v7 = *reinterpret_cast<const float4*>(s_cur + (size_t)r7 * N_PROBES + j);
        acc.x += v0.x + v1.x + v2.x + v3.x + v4.x + v5.x + v6.x + v7.x;
        acc.y += v0.y + v1.y + v2.y + v3.y + v4.y + v5.y + v6.y + v7.y;
        acc.z += v0.z + v1.z + v2.z + v3.z + v4.z + v5.z + v6.z + v7.z;
        acc.w += v0.w + v1.w + v2.w + v3.w + v4.w + v5.w + v6.w + v7.w;
    }
    for (; q < cnt; q++) {
        int r = csc_row[start + q];
        const float4 v = *reinterpret_cast<const float4*>(s_cur + (size_t)r * N_PROBES + j);
        acc.x += v.x; acc.y += v.y; acc.z += v.z; acc.w += v.w;
    }
    // acc = P_k[n] fragment (true probe vector). Write pre-scaled for next step.
    float4 sv = make_float4(acc.x * inv, acc.y * inv, acc.z * inv, acc.w * inv);
    *reinterpret_cast<float4*>(s_new + (size_t)n * N_PROBES + j) = sv;
    const float4 pr = *reinterpret_cast<const float4*>(probes + (size_t)n * N_PROBES + j);
    float dot = acc.x * pr.x + acc.y * pr.y + acc.z * pr.z + acc.w * pr.w;
    dot += __shfl_xor(dot, 4, 8);
    dot += __shfl_xor(dot, 2, 8);
    dot += __shfl_xor(dot, 1, 8);
    if ((gid & 7) == 0) diag_row[n] = dot * (1.0f / (float)N_PROBES);
}

// ---------------- out[n] = diags[n,:] @ W^T + b ----------------
__global__ void out_kernel(const float* __restrict__ diags, const float* __restrict__ W,
                           const float* __restrict__ b, float* __restrict__ out) {
    int n = blockIdx.x * blockDim.x + threadIdx.x;
    if (n >= N_NODES) return;
    float d[WALK_LEN];
#pragma unroll
    for (int k = 0; k < WALK_LEN; k++) d[k] = diags[(size_t)k * N_NODES + n];
    float o[OUT_DIM];
#pragma unroll
    for (int j = 0; j < OUT_DIM; j++) {
        float acc = b[j];
#pragma unroll
        for (int k = 0; k < WALK_LEN; k++) acc += d[k] * W[j * WALK_LEN + k];
        o[j] = acc;
    }
    float4* outp = reinterpret_cast<float4*>(out + (size_t)n * OUT_DIM);
    outp[0] = make_float4(o[0], o[1], o[2], o[3]);
    outp[1] = make_float4(o[4], o[5], o[6], o[7]);
}

extern "C" void kernel_launch(void* const* d_in, const int* in_sizes, int n_in,
                              void* d_out, int out_size, void* d_ws, size_t ws_size,
                              hipStream_t stream) {
    const int*   edge_index = (const int*)d_in[0];
    const int*   row    = edge_index;
    const int*   col    = edge_index + N_EDGES;
    const float* probes = (const float*)d_in[2];
    const float* W      = (const float*)d_in[3];
    const float* b      = (const float*)d_in[4];
    float*       out    = (float*)d_out;

    // workspace carve-up (256B aligned)
    char* ws = (char*)d_ws;
    size_t off = 0;
    auto carve = [&](size_t bytes) -> void* {
        void* p = ws + off;
        off += (bytes + 255) & ~(size_t)255;
        return p;
    };
    int*   outdeg  = (int*)  carve((size_t)N_NODES * 4);            // 400 KB
    int*   indeg   = (int*)  carve((size_t)N_NODES * 4);            // 400 KB
    int*   offs    = (int*)  carve((size_t)N_NODES * 4);            // 400 KB
    float* inv_od  = (float*)carve((size_t)N_NODES * 4);            // 400 KB
    int*   bsum    = (int*)  carve((size_t)NBLK * 4);               // ~1.6 KB
    int*   ticket  = (int*)  carve((size_t)N_EDGES * 4);            // 6.4 MB
    int*   csc_row = (int*)  carve((size_t)N_EDGES * 4);            // 6.4 MB
    float* bufA    = (float*)carve((size_t)N_NODES * N_PROBES * 4); // 12.8 MB
    float* bufB    = (float*)carve((size_t)N_NODES * N_PROBES * 4); // 12.8 MB
    float* diags   = (float*)carve((size_t)WALK_LEN * N_NODES * 4); // 6.4 MB

    hipMemsetAsync(outdeg, 0, (size_t)N_NODES * 4, stream);
    hipMemsetAsync(indeg,  0, (size_t)N_NODES * 4, stream);

    const int B = 256;
    // ---- build CSC (once per call, reused by 16 transitions) ----
    deg_ticket_kernel<<<(N_EDGES + B - 1) / B, B, 0, stream>>>(row, col, outdeg, indeg, ticket);
    inv_kernel  <<<(N_NODES + B - 1) / B, B, 0, stream>>>(outdeg, inv_od);
    scan1_kernel<<<NBLK, SCAN_BLK, 0, stream>>>(indeg, bsum);
    scan2_kernel<<<1, 512, 0, stream>>>(bsum);
    scan3_kernel<<<NBLK, SCAN_BLK, 0, stream>>>(indeg, bsum, offs);
    place_kernel<<<(N_EDGES + B - 1) / B, B, 0, stream>>>(row, col, ticket, offs, csc_row);

    // ---- s0 = probes * inv_outdeg ----
    s0_kernel<<<(N_NODES * N_PROBES) / B, B, 0, stream>>>(probes, inv_od, bufB);

    // ---- 16 fused transition + diag steps (no atomics) ----
    const float* cur = bufB;   // s_0
    for (int k = 0; k < WALK_LEN; k++) {
        float* nxt = (k & 1) ? bufB : bufA;   // k=0 writes bufA, k=1 writes bufB (s0 consumed), ...
        gather_kernel<<<(N_NODES * 8 + B - 1) / B, B, 0, stream>>>(
            offs, indeg, csc_row, cur, probes, inv_od, nxt, diags + (size_t)k * N_NODES);
        cur = nxt;
    }

    out_kernel<<<(N_NODES + B - 1) / B, B, 0, stream>>>(diags, W, b, out);
}

// Round 5
// 745.923 us; speedup vs baseline: 14.1690x; 1.0275x over previous
//
#include <hip/hip_runtime.h>

#define N_NODES   100000
#define N_EDGES   1600000
#define WALK_LEN  16
#define OUT_DIM   8
#define N_PROBES  32

#define SCAN_BLK  256
#define NBLK      ((N_NODES + SCAN_BLK - 1) / SCAN_BLK)   // 391

// ---- LDS-histogram build parameters ----
#define HB        64                       // histogram blocks
#define SLICE     (N_EDGES / HB)           // 25000 edges per block (exact)
#define BINS      25600                    // bins per pass (100 KB LDS as uint)
#define NPASS     4                        // 4*25600 = 102400 >= N_NODES

// ---------------- per-block partial histogram (LDS atomics only) ----------------
// partial[(p*HB + b)*BINS + bin] = count of arr[e]==p*BINS+bin within block b's slice
__global__ void hist_kernel(const int* __restrict__ arr, unsigned short* __restrict__ partial) {
    __shared__ unsigned int cnt[BINS];
    int b = blockIdx.x;
    int t = threadIdx.x;                   // 1024 threads
    for (int p = 0; p < NPASS; p++) {
        int base = p * BINS;
        for (int i = t; i < BINS; i += 1024) cnt[i] = 0;
        __syncthreads();
        for (int i = t; i < SLICE; i += 1024) {
            int v = arr[b * SLICE + i];
            if (v >= base && v < base + BINS) atomicAdd(&cnt[v - base], 1u);
        }
        __syncthreads();
        unsigned short* dst = partial + ((size_t)p * HB + b) * BINS;
        for (int i = t; i < BINS; i += 1024) dst[i] = (unsigned short)cnt[i];
        __syncthreads();
    }
}

// ---------------- outdeg = sum over blocks; emit 1/max(outdeg,1) ----------------
__global__ void reduce_out_kernel(const unsigned short* __restrict__ partial,
                                  float* __restrict__ inv_outdeg) {
    int n = blockIdx.x * blockDim.x + threadIdx.x;
    if (n >= N_NODES) return;
    int p = n / BINS;
    int bin = n - p * BINS;
    int sum = 0;
    for (int b = 0; b < HB; b++) sum += partial[((size_t)p * HB + b) * BINS + bin];
    inv_outdeg[n] = 1.0f / (float)(sum > 0 ? sum : 1);
}

// ---------------- indeg = sum; overwrite partial with exclusive prefix over blocks ----------------
__global__ void reduce_scan_col_kernel(unsigned short* __restrict__ partial,
                                       int* __restrict__ indeg) {
    int n = blockIdx.x * blockDim.x + threadIdx.x;
    if (n >= N_NODES) return;
    int p = n / BINS;
    int bin = n - p * BINS;
    int run = 0;
    for (int b = 0; b < HB; b++) {
        size_t idx = ((size_t)p * HB + b) * BINS + bin;
        int c = partial[idx];
        partial[idx] = (unsigned short)run;
        run += c;
    }
    indeg[n] = run;
}

// ---------------- prefix scan of indeg -> offs (exclusive) ----------------
__global__ void scan1_kernel(const int* __restrict__ indeg, int* __restrict__ bsum) {
    __shared__ int s[SCAN_BLK];
    int i = blockIdx.x * SCAN_BLK + threadIdx.x;
    s[threadIdx.x] = (i < N_NODES) ? indeg[i] : 0;
    __syncthreads();
    for (int o = SCAN_BLK / 2; o > 0; o >>= 1) {
        if (threadIdx.x < o) s[threadIdx.x] += s[threadIdx.x + o];
        __syncthreads();
    }
    if (threadIdx.x == 0) bsum[blockIdx.x] = s[0];
}

__global__ void scan2_kernel(int* __restrict__ bsum) {   // single block of 512
    __shared__ int s[512];
    int t = threadIdx.x;
    s[t] = (t < NBLK) ? bsum[t] : 0;
    __syncthreads();
    for (int o = 1; o < 512; o <<= 1) {
        int v = (t >= o) ? s[t - o] : 0;
        __syncthreads();
        s[t] += v;
        __syncthreads();
    }
    if (t < NBLK) bsum[t] = (t == 0) ? 0 : s[t - 1];     // exclusive
}

__global__ void scan3_kernel(const int* __restrict__ indeg, const int* __restrict__ bsum,
                             int* __restrict__ offs) {
    __shared__ int s[SCAN_BLK];
    int t = threadIdx.x;
    int i = blockIdx.x * SCAN_BLK + t;
    int v = (i < N_NODES) ? indeg[i] : 0;
    s[t] = v;
    __syncthreads();
    for (int o = 1; o < SCAN_BLK; o <<= 1) {
        int u = (t >= o) ? s[t - o] : 0;
        __syncthreads();
        s[t] += u;
        __syncthreads();
    }
    if (i < N_NODES) offs[i] = bsum[blockIdx.x] + s[t] - v;   // exclusive
}

// ---------------- CSC fill: LDS rank counters, zero global atomics ----------------
__global__ void place_kernel(const int* __restrict__ row, const int* __restrict__ col,
                             const int* __restrict__ offs,
                             const unsigned short* __restrict__ pbase,
                             int* __restrict__ csc_row) {
    __shared__ unsigned int cnt[BINS];
    int b = blockIdx.x;
    int t = threadIdx.x;                   // 1024 threads
    for (int p = 0; p < NPASS; p++) {
        int base = p * BINS;
        for (int i = t; i < BINS; i += 1024) cnt[i] = 0;
        __syncthreads();
        const unsigned short* pb = pbase + ((size_t)p * HB + b) * BINS;
        for (int i = t; i < SLICE; i += 1024) {
            int e = b * SLICE + i;
            int c = col[e];
            if (c >= base && c < base + BINS) {
                unsigned int rank = atomicAdd(&cnt[c - base], 1u);
                int slot = offs[c] + (int)pb[c - base] + (int)rank;
                csc_row[slot] = row[e];
            }
        }
        __syncthreads();
    }
}

// ---------------- s0 = probes * inv_outdeg ----------------
__global__ void s0_kernel(const float* __restrict__ probes, const float* __restrict__ inv_outdeg,
                          float* __restrict__ s0) {
    int gid = blockIdx.x * blockDim.x + threadIdx.x;   // [0, N*32)
    s0[gid] = probes[gid] * inv_outdeg[gid >> 5];
}

// ---------------- fused unweighted gather + rescale + Hutchinson diag ----------------
// 8 threads per node; thread (n, j) owns probes [4j, 4j+4).
__global__ void gather_kernel(const int* __restrict__ offs, const int* __restrict__ indeg,
                              const int* __restrict__ csc_row,
                              const float* __restrict__ s_cur, const float* __restrict__ probes,
                              const float* __restrict__ inv_outdeg,
                              float* __restrict__ s_new, float* __restrict__ diag_row) {
    int gid = blockIdx.x * blockDim.x + threadIdx.x;   // [0, N*8) exact
    int n = gid >> 3;
    int j = (gid & 7) << 2;
    int start = offs[n];
    int cnt   = indeg[n];
    float inv = inv_outdeg[n];
    float4 acc = make_float4(0.f, 0.f, 0.f, 0.f);
    int q = 0;
    for (; q + 8 <= cnt; q += 8) {
        int r0 = csc_row[start + q + 0];
        int r1 = csc_row[start + q + 1];
        int r2 = csc_row[start + q + 2];
        int r3 = csc_row[start + q + 3];
        int r4 = csc_row[start + q + 4];
        int r5 = csc_row[start + q + 5];
        int r6 = csc_row[start + q + 6];
        int r7 = csc_row[start + q + 7];
        float4 v0 = *reinterpret_cast<const float4*>(s_cur + (size_t)r0 * N_PROBES + j);
        float4 v1 = *reinterpret_cast<const float4*>(s_cur + (size_t)r1 * N_PROBES + j);
        float4 v2 = *reinterpret_cast<const float4*>(s_cur + (size_t)r2 * N_PROBES + j);
        float4 v3 = *reinterpret_cast<const float4*>(s_cur + (size_t)r3 * N_PROBES + j);
        float4 v4 = *reinterpret_cast<const float4*>(s_cur + (size_t)r4 * N_PROBES + j);
        float4 v5 = *reinterpret_cast<const float4*>(s_cur + (size_t)r5 * N_PROBES + j);
        float4 v6 = *reinterpret_cast<const float4*>(s_cur + (size_t)r6 * N_PROBES + j);
        float4 v7 = *reinterpret_cast<const float4*>(s_cur + (size_t)r7 * N_PROBES + j);
        acc.x += v0.x + v1.x + v2.x + v3.x + v4.x + v5.x + v6.x + v7.x;
        acc.y += v0.y + v1.y + v2.y + v3.y + v4.y + v5.y + v6.y + v7.y;
        acc.z += v0.z + v1.z + v2.z + v3.z + v4.z + v5.z + v6.z + v7.z;
        acc.w += v0.w + v1.w + v2.w + v3.w + v4.w + v5.w + v6.w + v7.w;
    }
    for (; q < cnt; q++) {
        int r = csc_row[start + q];
        const float4 v = *reinterpret_cast<const float4*>(s_cur + (size_t)r * N_PROBES + j);
        acc.x += v.x; acc.y += v.y; acc.z += v.z; acc.w += v.w;
    }
    // acc = P_k[n] fragment (true probe vector). Write pre-scaled for next step.
    float4 sv = make_float4(acc.x * inv, acc.y * inv, acc.z * inv, acc.w * inv);
    *reinterpret_cast<float4*>(s_new + (size_t)n * N_PROBES + j) = sv;
    const float4 pr = *reinterpret_cast<const float4*>(probes + (size_t)n * N_PROBES + j);
    float dot = acc.x * pr.x + acc.y * pr.y + acc.z * pr.z + acc.w * pr.w;
    dot += __shfl_xor(dot, 4, 8);
    dot += __shfl_xor(dot, 2, 8);
    dot += __shfl_xor(dot, 1, 8);
    if ((gid & 7) == 0) diag_row[n] = dot * (1.0f / (float)N_PROBES);
}

// ---------------- out[n] = diags[n,:] @ W^T + b ----------------
__global__ void out_kernel(const float* __restrict__ diags, const float* __restrict__ W,
                           const float* __restrict__ b, float* __restrict__ out) {
    int n = blockIdx.x * blockDim.x + threadIdx.x;
    if (n >= N_NODES) return;
    float d[WALK_LEN];
#pragma unroll
    for (int k = 0; k < WALK_LEN; k++) d[k] = diags[(size_t)k * N_NODES + n];
    float o[OUT_DIM];
#pragma unroll
    for (int j = 0; j < OUT_DIM; j++) {
        float acc = b[j];
#pragma unroll
        for (int k = 0; k < WALK_LEN; k++) acc += d[k] * W[j * WALK_LEN + k];
        o[j] = acc;
    }
    float4* outp = reinterpret_cast<float4*>(out + (size_t)n * OUT_DIM);
    outp[0] = make_float4(o[0], o[1], o[2], o[3]);
    outp[1] = make_float4(o[4], o[5], o[6], o[7]);
}

extern "C" void kernel_launch(void* const* d_in, const int* in_sizes, int n_in,
                              void* d_out, int out_size, void* d_ws, size_t ws_size,
                              hipStream_t stream) {
    const int*   edge_index = (const int*)d_in[0];
    const int*   row    = edge_index;
    const int*   col    = edge_index + N_EDGES;
    const float* probes = (const float*)d_in[2];
    const float* W      = (const float*)d_in[3];
    const float* b      = (const float*)d_in[4];
    float*       out    = (float*)d_out;

    // workspace carve-up (256B aligned)
    char* ws = (char*)d_ws;
    size_t off = 0;
    auto carve = [&](size_t bytes) -> void* {
        void* p = ws + off;
        off += (bytes + 255) & ~(size_t)255;
        return p;
    };
    int*            indeg   = (int*)           carve((size_t)N_NODES * 4);            // 400 KB
    int*            offs    = (int*)           carve((size_t)N_NODES * 4);            // 400 KB
    float*          inv_od  = (float*)         carve((size_t)N_NODES * 4);            // 400 KB
    int*            bsum    = (int*)           carve((size_t)NBLK * 4);               // ~1.6 KB
    unsigned short* partial = (unsigned short*)carve((size_t)NPASS * HB * BINS * 2);  // 13.1 MB
    int*            csc_row = (int*)           carve((size_t)N_EDGES * 4);            // 6.4 MB
    float*          bufA    = (float*)         carve((size_t)N_NODES * N_PROBES * 4); // 12.8 MB
    float*          bufB    = (float*)         carve((size_t)N_NODES * N_PROBES * 4); // 12.8 MB
    float*          diags   = (float*)         carve((size_t)WALK_LEN * N_NODES * 4); // 6.4 MB

    const int B = 256;
    // ---- build CSC + inv_outdeg, zero global atomics ----
    hist_kernel<<<HB, 1024, 0, stream>>>(row, partial);
    reduce_out_kernel<<<NBLK, B, 0, stream>>>(partial, inv_od);
    hist_kernel<<<HB, 1024, 0, stream>>>(col, partial);
    reduce_scan_col_kernel<<<NBLK, B, 0, stream>>>(partial, indeg);
    scan1_kernel<<<NBLK, SCAN_BLK, 0, stream>>>(indeg, bsum);
    scan2_kernel<<<1, 512, 0, stream>>>(bsum);
    scan3_kernel<<<NBLK, SCAN_BLK, 0, stream>>>(indeg, bsum, offs);
    place_kernel<<<HB, 1024, 0, stream>>>(row, col, offs, partial, csc_row);

    // ---- s0 = probes * inv_outdeg ----
    s0_kernel<<<(N_NODES * N_PROBES) / B, B, 0, stream>>>(probes, inv_od, bufB);

    // ---- 16 fused transition + diag steps (no atomics) ----
    const float* cur = bufB;   // s_0
    for (int k = 0; k < WALK_LEN; k++) {
        float* nxt = (k & 1) ? bufB : bufA;
        gather_kernel<<<(N_NODES * 8 + B - 1) / B, B, 0, stream>>>(
            offs, indeg, csc_row, cur, probes, inv_od, nxt, diags + (size_t)k * N_NODES);
        cur = nxt;
    }

    out_kernel<<<(N_NODES + B - 1) / B, B, 0, stream>>>(diags, W, b, out);
}

// Round 6
// 669.494 us; speedup vs baseline: 15.7866x; 1.1142x over previous
//
#include <hip/hip_runtime.h>

#define N_NODES   100000
#define N_EDGES   1600000
#define WALK_LEN  16
#define OUT_DIM   8
#define N_PROBES  32

#define SCAN_BLK  256
#define NBLK      ((N_NODES + SCAN_BLK - 1) / SCAN_BLK)   // 391

// ---- LDS byte-counter build parameters ----
#define HB        128                      // histogram blocks
#define SLICE     (N_EDGES / HB)           // 12500 edges per block (exact)
#define NWORDS    (N_NODES / 4)            // 25000 packed uints = 100 KB LDS

// ---------------- per-block byte-packed histogram (single pass, LDS atomics) ----------------
// partial[b*N_NODES + n] (uchar) = count of arr[e]==n within block b's slice
__global__ void hist_kernel(const int* __restrict__ arr, unsigned char* __restrict__ partial) {
    __shared__ unsigned int cnt[NWORDS];
    int b = blockIdx.x;
    int t = threadIdx.x;                   // 1024 threads
    for (int i = t; i < NWORDS; i += 1024) cnt[i] = 0;
    __syncthreads();
    const int* a = arr + b * SLICE;
    for (int i = t; i < SLICE; i += 1024) {
        int v = a[i];
        atomicAdd(&cnt[v >> 2], 1u << ((v & 3) * 8));
    }
    __syncthreads();
    unsigned int* dst = (unsigned int*)(partial + (size_t)b * N_NODES);
    for (int i = t; i < NWORDS; i += 1024) dst[i] = cnt[i];
}

// ---------------- outdeg = byte-sum over blocks; emit 1/max(outdeg,1) ----------------
__global__ void reduce_out_kernel(const unsigned char* __restrict__ partial,
                                  float* __restrict__ inv_outdeg) {
    int q = blockIdx.x * blockDim.x + threadIdx.x;   // word index, [0, NWORDS)
    if (q >= NWORDS) return;
    int s0 = 0, s1 = 0, s2 = 0, s3 = 0;
    for (int b = 0; b < HB; b++) {
        unsigned int w = *(const unsigned int*)(partial + (size_t)b * N_NODES + q * 4);
        s0 += w & 0xFF; s1 += (w >> 8) & 0xFF; s2 += (w >> 16) & 0xFF; s3 += (w >> 24) & 0xFF;
    }
    int n = q * 4;
    inv_outdeg[n + 0] = 1.0f / (float)(s0 > 0 ? s0 : 1);
    inv_outdeg[n + 1] = 1.0f / (float)(s1 > 0 ? s1 : 1);
    inv_outdeg[n + 2] = 1.0f / (float)(s2 > 0 ? s2 : 1);
    inv_outdeg[n + 3] = 1.0f / (float)(s3 > 0 ? s3 : 1);
}

// ---------------- indeg = byte-sum; overwrite partial with exclusive prefix over blocks ----------------
__global__ void reduce_scan_col_kernel(unsigned char* __restrict__ partial,
                                       int* __restrict__ indeg) {
    int q = blockIdx.x * blockDim.x + threadIdx.x;   // word index, [0, NWORDS)
    if (q >= NWORDS) return;
    unsigned int r0 = 0, r1 = 0, r2 = 0, r3 = 0;     // running prefixes (fit in a byte)
    for (int b = 0; b < HB; b++) {
        unsigned int* p = (unsigned int*)(partial + (size_t)b * N_NODES + q * 4);
        unsigned int w = *p;
        *p = (r0 & 0xFF) | ((r1 & 0xFF) << 8) | ((r2 & 0xFF) << 16) | ((r3 & 0xFF) << 24);
        r0 += w & 0xFF; r1 += (w >> 8) & 0xFF; r2 += (w >> 16) & 0xFF; r3 += (w >> 24) & 0xFF;
    }
    int n = q * 4;
    indeg[n + 0] = (int)r0;
    indeg[n + 1] = (int)r1;
    indeg[n + 2] = (int)r2;
    indeg[n + 3] = (int)r3;
}

// ---------------- prefix scan of indeg -> offs (exclusive) ----------------
__global__ void scan1_kernel(const int* __restrict__ indeg, int* __restrict__ bsum) {
    __shared__ int s[SCAN_BLK];
    int i = blockIdx.x * SCAN_BLK + threadIdx.x;
    s[threadIdx.x] = (i < N_NODES) ? indeg[i] : 0;
    __syncthreads();
    for (int o = SCAN_BLK / 2; o > 0; o >>= 1) {
        if (threadIdx.x < o) s[threadIdx.x] += s[threadIdx.x + o];
        __syncthreads();
    }
    if (threadIdx.x == 0) bsum[blockIdx.x] = s[0];
}

__global__ void scan2_kernel(int* __restrict__ bsum) {   // single block of 512
    __shared__ int s[512];
    int t = threadIdx.x;
    s[t] = (t < NBLK) ? bsum[t] : 0;
    __syncthreads();
    for (int o = 1; o < 512; o <<= 1) {
        int v = (t >= o) ? s[t - o] : 0;
        __syncthreads();
        s[t] += v;
        __syncthreads();
    }
    if (t < NBLK) bsum[t] = (t == 0) ? 0 : s[t - 1];     // exclusive
}

__global__ void scan3_kernel(const int* __restrict__ indeg, const int* __restrict__ bsum,
                             int* __restrict__ offs) {
    __shared__ int s[SCAN_BLK];
    int t = threadIdx.x;
    int i = blockIdx.x * SCAN_BLK + t;
    int v = (i < N_NODES) ? indeg[i] : 0;
    s[t] = v;
    __syncthreads();
    for (int o = 1; o < SCAN_BLK; o <<= 1) {
        int u = (t >= o) ? s[t - o] : 0;
        __syncthreads();
        s[t] += u;
        __syncthreads();
    }
    if (i < N_NODES) offs[i] = bsum[blockIdx.x] + s[t] - v;   // exclusive
}

// ---------------- CSC fill: LDS byte rank counters seeded with prefix base ----------------
__global__ void place_kernel(const int* __restrict__ row, const int* __restrict__ col,
                             const int* __restrict__ offs,
                             const unsigned char* __restrict__ pbase,
                             int* __restrict__ csc_row) {
    __shared__ unsigned int cnt[NWORDS];
    int b = blockIdx.x;
    int t = threadIdx.x;                   // 1024 threads
    const unsigned int* src = (const unsigned int*)(pbase + (size_t)b * N_NODES);
    for (int i = t; i < NWORDS; i += 1024) cnt[i] = src[i];   // seed with prefix-base bytes
    __syncthreads();
    for (int i = t; i < SLICE; i += 1024) {
        int e = b * SLICE + i;
        int c = col[e];
        int sh = (c & 3) * 8;
        unsigned int old = atomicAdd(&cnt[c >> 2], 1u << sh);
        int pos = (int)((old >> sh) & 0xFF);               // prefix-base + in-block rank
        csc_row[offs[c] + pos] = row[e];
    }
}

// ---------------- s0 = probes * inv_outdeg ----------------
__global__ void s0_kernel(const float* __restrict__ probes, const float* __restrict__ inv_outdeg,
                          float* __restrict__ s0) {
    int gid = blockIdx.x * blockDim.x + threadIdx.x;   // [0, N*32)
    s0[gid] = probes[gid] * inv_outdeg[gid >> 5];
}

// ---------------- fused unweighted gather + rescale + Hutchinson diag ----------------
// 8 threads per node; thread (n, j) owns probes [4j, 4j+4).
__global__ void gather_kernel(const int* __restrict__ offs, const int* __restrict__ indeg,
                              const int* __restrict__ csc_row,
                              const float* __restrict__ s_cur, const float* __restrict__ probes,
                              const float* __restrict__ inv_outdeg,
                              float* __restrict__ s_new, float* __restrict__ diag_row) {
    int gid = blockIdx.x * blockDim.x + threadIdx.x;   // [0, N*8) exact
    int n = gid >> 3;
    int j = (gid & 7) << 2;
    int start = offs[n];
    int cnt   = indeg[n];
    float inv = inv_outdeg[n];
    float4 acc = make_float4(0.f, 0.f, 0.f, 0.f);
    int q = 0;
    for (; q + 8 <= cnt; q += 8) {
        int r0 = csc_row[start + q + 0];
        int r1 = csc_row[start + q + 1];
        int r2 = csc_row[start + q + 2];
        int r3 = csc_row[start + q + 3];
        int r4 = csc_row[start + q + 4];
        int r5 = csc_row[start + q + 5];
        int r6 = csc_row[start + q + 6];
        int r7 = csc_row[start + q + 7];
        float4 v0 = *reinterpret_cast<const float4*>(s_cur + (size_t)r0 * N_PROBES + j);
        float4 v1 = *reinterpret_cast<const float4*>(s_cur + (size_t)r1 * N_PROBES + j);
        float4 v2 = *reinterpret_cast<const float4*>(s_cur + (size_t)r2 * N_PROBES + j);
        float4 v3 = *reinterpret_cast<const float4*>(s_cur + (size_t)r3 * N_PROBES + j);
        float4 v4 = *reinterpret_cast<const float4*>(s_cur + (size_t)r4 * N_PROBES + j);
        float4 v5 = *reinterpret_cast<const float4*>(s_cur + (size_t)r5 * N_PROBES + j);
        float4 v6 = *reinterpret_cast<const float4*>(s_cur + (size_t)r6 * N_PROBES + j);
        float4 v7 = *reinterpret_cast<const float4*>(s_cur + (size_t)r7 * N_PROBES + j);
        acc.x += v0.x + v1.x + v2.x + v3.x + v4.x + v5.x + v6.x + v7.x;
        acc.y += v0.y + v1.y + v2.y + v3.y + v4.y + v5.y + v6.y + v7.y;
        acc.z += v0.z + v1.z + v2.z + v3.z + v4.z + v5.z + v6.z + v7.z;
        acc.w += v0.w + v1.w + v2.w + v3.w + v4.w + v5.w + v6.w + v7.w;
    }
    for (; q < cnt; q++) {
        int r = csc_row[start + q];
        const float4 v = *reinterpret_cast<const float4*>(s_cur + (size_t)r * N_PROBES + j);
        acc.x += v.x; acc.y += v.y; acc.z += v.z; acc.w += v.w;
    }
    // acc = P_k[n] fragment (true probe vector). Write pre-scaled for next step.
    float4 sv = make_float4(acc.x * inv, acc.y * inv, acc.z * inv, acc.w * inv);
    *reinterpret_cast<float4*>(s_new + (size_t)n * N_PROBES + j) = sv;
    const float4 pr = *reinterpret_cast<const float4*>(probes + (size_t)n * N_PROBES + j);
    float dot = acc.x * pr.x + acc.y * pr.y + acc.z * pr.z + acc.w * pr.w;
    dot += __shfl_xor(dot, 4, 8);
    dot += __shfl_xor(dot, 2, 8);
    dot += __shfl_xor(dot, 1, 8);
    if ((gid & 7) == 0) diag_row[n] = dot * (1.0f / (float)N_PROBES);
}

// ---------------- out[n] = diags[n,:] @ W^T + b ----------------
__global__ void out_kernel(const float* __restrict__ diags, const float* __restrict__ W,
                           const float* __restrict__ b, float* __restrict__ out) {
    int n = blockIdx.x * blockDim.x + threadIdx.x;
    if (n >= N_NODES) return;
    float d[WALK_LEN];
#pragma unroll
    for (int k = 0; k < WALK_LEN; k++) d[k] = diags[(size_t)k * N_NODES + n];
    float o[OUT_DIM];
#pragma unroll
    for (int j = 0; j < OUT_DIM; j++) {
        float acc = b[j];
#pragma unroll
        for (int k = 0; k < WALK_LEN; k++) acc += d[k] * W[j * WALK_LEN + k];
        o[j] = acc;
    }
    float4* outp = reinterpret_cast<float4*>(out + (size_t)n * OUT_DIM);
    outp[0] = make_float4(o[0], o[1], o[2], o[3]);
    outp[1] = make_float4(o[4], o[5], o[6], o[7]);
}

extern "C" void kernel_launch(void* const* d_in, const int* in_sizes, int n_in,
                              void* d_out, int out_size, void* d_ws, size_t ws_size,
                              hipStream_t stream) {
    const int*   edge_index = (const int*)d_in[0];
    const int*   row    = edge_index;
    const int*   col    = edge_index + N_EDGES;
    const float* probes = (const float*)d_in[2];
    const float* W      = (const float*)d_in[3];
    const float* b      = (const float*)d_in[4];
    float*       out    = (float*)d_out;

    // workspace carve-up (256B aligned)
    char* ws = (char*)d_ws;
    size_t off = 0;
    auto carve = [&](size_t bytes) -> void* {
        void* p = ws + off;
        off += (bytes + 255) & ~(size_t)255;
        return p;
    };
    int*           indeg   = (int*)          carve((size_t)N_NODES * 4);            // 400 KB
    int*           offs    = (int*)          carve((size_t)N_NODES * 4);            // 400 KB
    float*         inv_od  = (float*)        carve((size_t)N_NODES * 4);            // 400 KB
    int*           bsum    = (int*)          carve((size_t)NBLK * 4);               // ~1.6 KB
    unsigned char* partial = (unsigned char*)carve((size_t)HB * N_NODES);           // 12.8 MB
    int*           csc_row = (int*)          carve((size_t)N_EDGES * 4);            // 6.4 MB
    float*         bufA    = (float*)        carve((size_t)N_NODES * N_PROBES * 4); // 12.8 MB
    float*         bufB    = (float*)        carve((size_t)N_NODES * N_PROBES * 4); // 12.8 MB
    float*         diags   = (float*)        carve((size_t)WALK_LEN * N_NODES * 4); // 6.4 MB

    const int B = 256;
    // ---- build CSC + inv_outdeg, zero global atomics, single pass per histogram ----
    hist_kernel<<<HB, 1024, 0, stream>>>(row, partial);
    reduce_out_kernel<<<(NWORDS + B - 1) / B, B, 0, stream>>>(partial, inv_od);
    hist_kernel<<<HB, 1024, 0, stream>>>(col, partial);
    reduce_scan_col_kernel<<<(NWORDS + B - 1) / B, B, 0, stream>>>(partial, indeg);
    scan1_kernel<<<NBLK, SCAN_BLK, 0, stream>>>(indeg, bsum);
    scan2_kernel<<<1, 512, 0, stream>>>(bsum);
    scan3_kernel<<<NBLK, SCAN_BLK, 0, stream>>>(indeg, bsum, offs);
    place_kernel<<<HB, 1024, 0, stream>>>(row, col, offs, partial, csc_row);

    // ---- s0 = probes * inv_outdeg ----
    s0_kernel<<<(N_NODES * N_PROBES) / B, B, 0, stream>>>(probes, inv_od, bufB);

    // ---- 16 fused transition + diag steps (no atomics) ----
    const float* cur = bufB;   // s_0
    for (int k = 0; k < WALK_LEN; k++) {
        float* nxt = (k & 1) ? bufB : bufA;
        gather_kernel<<<(N_NODES * 8 + B - 1) / B, B, 0, stream>>>(
            offs, indeg, csc_row, cur, probes, inv_od, nxt, diags + (size_t)k * N_NODES);
        cur = nxt;
    }

    out_kernel<<<(N_NODES + B - 1) / B, B, 0, stream>>>(diags, W, b, out);
}